// Round 8
// baseline (91.986 us; speedup 1.0000x reference)
//
#include <hip/hip_runtime.h>
#include <hip/hip_bf16.h>
#include <math.h>

#define BB 32
#define TTOT 1024
#define KK 16
#define DD 80
#define PP 64

// workspace layout (float offsets)
#define WS_NUNIQ  0        // 1
#define WS_MASK   8        // 64
#define WS_DCONST 128      // 512 = B*K
#define WS_CVEC   1024     // 512*80 -> ends 41984
#define WS_PART2  41984    // 2048 (k2 per-block partials) -> 44032
#define WS_PART3L 44032    // 1600 (k3_lreg per-block partials) -> 45632
#define WS_PART3M 45632    // 64 (k3_mureg per-block partials) -> 45696
#define WS_XBF16  46080    // bf16[32*1024*80] = 1,310,720 floats -> ends 1,356,800
#define WS_MINVB  1356800  // bf16[512*80*80]  = 1,638,400 floats -> ends 2,995,200 (12.0 MB)

typedef short bf16x8 __attribute__((ext_vector_type(8)));
typedef float f32x4 __attribute__((ext_vector_type(4)));

__device__ __forceinline__ float wave_sum(float v) {
#pragma unroll
  for (int o = 32; o > 0; o >>= 1) v += __shfl_down(v, o);
  return v;
}

__device__ __forceinline__ unsigned short f2bf(float f) {
  __hip_bfloat16 h = __float2bfloat16(f);
  return *reinterpret_cast<unsigned short*>(&h);
}

// ---- K0: subject mask + n_unique ----
__global__ void k0_mask(const int* __restrict__ sids, float* __restrict__ ws) {
  int tid = threadIdx.x;  // 64 threads, one per subject slot
  int found = 0;
  for (int b = 0; b < BB; ++b) found |= (sids[b] == tid) ? 1 : 0;
  ws[WS_MASK + tid] = (float)found;
  unsigned long long bal = __ballot(found != 0);
  if (tid == 0) ws[WS_NUNIQ] = (float)__popcll(bal);
}

// ---- KX: x fp32 -> bf16 (same layout) ----
__global__ __launch_bounds__(256) void kx_cast(const float* __restrict__ x,
                                               float* __restrict__ ws) {
  size_t idx = (size_t)blockIdx.x * 256 + threadIdx.x;  // one per 4 floats
  float4 v = reinterpret_cast<const float4*>(x)[idx];
  uint2 o;
  o.x = ((unsigned)f2bf(v.y) << 16) | f2bf(v.x);
  o.y = ((unsigned)f2bf(v.w) << 16) | f2bf(v.z);
  reinterpret_cast<uint2*>((__hip_bfloat16*)(ws + WS_XBF16))[idx] = o;
}

// ---- K1: per (b,k) triangular inverse; emit Minv as bf16, c fp32, dconst ----
// Whole solution y[80] lives in registers as five named 16-arrays; all loops
// 16-bounded + fully unrolled -> static indices only (R4: 80-deep unroll was
// refused -> scratch; R6/R7: LDS round-trip in the solve = latency-bound chain
// at 4 waves/CU, VALUBusy 9%). Cross-chunk terms are independent FMAs fed by
// contiguous-row s_loads the scheduler can hoist.
#define K1_CROSS(CI, CP, YP)                                              \
  _Pragma("unroll")                                                       \
  for (int m = 0; m < 16; ++m) {                                          \
    float ym = YP[m];                                                     \
    _Pragma("unroll")                                                     \
    for (int ii = 0; ii < 16; ++ii)                                       \
      s[ii] = fmaf(-Lg[((CI)*16 + ii) * DD + ((CP)*16 + m)], ym, s[ii]);  \
  }

#define K1_SOLVE(CI, YC, CROSS_BODY)                                      \
  {                                                                       \
    float s[16];                                                          \
    _Pragma("unroll")                                                     \
    for (int ii = 0; ii < 16; ++ii)                                       \
      s[ii] = ((CI)*16 + ii == j) ? 1.0f : 0.0f;                          \
    CROSS_BODY                                                            \
    _Pragma("unroll")                                                     \
    for (int ii = 0; ii < 16; ++ii) {                                     \
      float v = s[ii];                                                    \
      _Pragma("unroll")                                                   \
      for (int mm = 0; mm < 16; ++mm)                                     \
        if (mm < ii)                                                      \
          v = fmaf(-Lg[((CI)*16 + ii) * DD + ((CI)*16 + mm)], YC[mm], v); \
      YC[ii] = v * rdiag[(CI)*16 + ii];                                   \
    }                                                                     \
  }

__global__ __launch_bounds__(128, 1) void k1_inv(const float* __restrict__ L_subj,
                                                 const float* __restrict__ mu_subj,
                                                 const int* __restrict__ sids,
                                                 float* __restrict__ ws) {
  int k = blockIdx.x, b = blockIdx.y;
  int p = sids[b];
  const float* Lg = L_subj + ((size_t)(p * KK + k)) * DD * DD;   // block-uniform -> s_load
  const float* mug = mu_subj + (size_t)(p * KK + k) * DD;
  int bk = b * KK + k;

  __shared__ float ys[DD * 81];
  __shared__ float rdiag[DD];
  __shared__ float lgd[DD];

  int tid = threadIdx.x;
  if (tid < DD) {
    float dv = Lg[tid * DD + tid];
    rdiag[tid] = 1.0f / dv;
    lgd[tid] = logf(dv);
  }
  __syncthreads();

  const int j = tid;  // column of Minv this thread solves: L y = e_j
  float y0[16], y1[16], y2[16], y3[16], y4[16];
  K1_SOLVE(0, y0, )
  K1_SOLVE(1, y1, K1_CROSS(1, 0, y0))
  K1_SOLVE(2, y2, K1_CROSS(2, 0, y0) K1_CROSS(2, 1, y1))
  K1_SOLVE(3, y3, K1_CROSS(3, 0, y0) K1_CROSS(3, 1, y1) K1_CROSS(3, 2, y2))
  K1_SOLVE(4, y4, K1_CROSS(4, 0, y0) K1_CROSS(4, 1, y1) K1_CROSS(4, 2, y2)
                  K1_CROSS(4, 3, y3))

  if (j < DD) {
#pragma unroll
    for (int ii = 0; ii < 16; ++ii) {
      ys[(ii)      * 81 + j] = y0[ii];
      ys[(16 + ii) * 81 + j] = y1[ii];
      ys[(32 + ii) * 81 + j] = y2[ii];
      ys[(48 + ii) * 81 + j] = y3[ii];
      ys[(64 + ii) * 81 + j] = y4[ii];
    }
  }
  __syncthreads();

  // coalesced bf16 write of Minv rows (2 bf16 per uint)
  unsigned* Mg = reinterpret_cast<unsigned*>(
      (__hip_bfloat16*)(ws + WS_MINVB) + (size_t)bk * DD * DD);
  for (int idx = tid; idx < DD * (DD / 2); idx += 128) {
    int i = idx / (DD / 2), jp = idx % (DD / 2);
    unsigned u = ((unsigned)f2bf(ys[i * 81 + 2 * jp + 1]) << 16) | f2bf(ys[i * 81 + 2 * jp]);
    Mg[idx] = u;
  }

  if (tid < DD) {
    int i = tid;
    float ci = 0.f;
#pragma unroll 8
    for (int jj = 0; jj < DD; ++jj) ci = fmaf(ys[i * 81 + jj], mug[jj], ci);
    ws[WS_CVEC + bk * DD + i] = ci;
  }
  if (tid == 0) {
    float s = 0.f;
    for (int i = 0; i < DD; ++i) s += lgd[i];
    ws[WS_DCONST + bk] = (float)(0.5 * 80.0 * 1.8378770664093453) + s;  // 0.5*D*ln(2pi)+logdet
  }
}

// ---- K2: MFMA main loss. Block = (k, ttile of 256, b); 4 waves x 64 t. ----
// Writes ONE partial per block (no global atomics).
__global__ __launch_bounds__(256) void k2_mfma(const float* __restrict__ gamma,
                                               const float* __restrict__ ws,
                                               float* __restrict__ part) {
  const int k = blockIdx.x, tt = blockIdx.y, b = blockIdx.z;
  const int w = threadIdx.x >> 6, l = threadIdx.x & 63;
  const int lg = l >> 4, lr = l & 15;
  const int bk = b * KK + k;

  const __hip_bfloat16* Xb = (const __hip_bfloat16*)(ws + WS_XBF16) + (size_t)b * TTOT * DD;
  const __hip_bfloat16* Mb = (const __hip_bfloat16*)(ws + WS_MINVB) + (size_t)bk * DD * DD;
  const float* cc = ws + WS_CVEC + bk * DD;
  const float dconst = ws[WS_DCONST + bk];

  const int t0 = tt * 256 + w * 64;  // wave's t base

  f32x4 accf[5][4] = {};  // [m-tile][n-frag]
#pragma unroll
  for (int c = 0; c < 3; ++c) {
    const int j = c * 32 + lg * 8;
    const bool dead = (c == 2) && (lg >= 2);  // j >= 80: zero-pad K to 96
    bf16x8 af[5], bf[4];
#pragma unroll
    for (int mt = 0; mt < 5; ++mt)
      af[mt] = dead ? (bf16x8){} : *(const bf16x8*)(Mb + (mt * 16 + lr) * DD + j);
#pragma unroll
    for (int nf = 0; nf < 4; ++nf)
      bf[nf] = dead ? (bf16x8){} : *(const bf16x8*)(Xb + (size_t)(t0 + nf * 16 + lr) * DD + j);
#pragma unroll
    for (int mt = 0; mt < 5; ++mt)
#pragma unroll
      for (int nf = 0; nf < 4; ++nf)
        accf[mt][nf] = __builtin_amdgcn_mfma_f32_16x16x32_bf16(af[mt], bf[nf], accf[mt][nf], 0, 0, 0);
  }

  // epilogue: maha per t, gamma-weighted accumulate
  float c_r[5][4];
#pragma unroll
  for (int mt = 0; mt < 5; ++mt)
#pragma unroll
    for (int r = 0; r < 4; ++r)
      c_r[mt][r] = cc[mt * 16 + lg * 4 + r];  // row i = mt*16 + lg*4 + r

  float v = 0.f;
#pragma unroll
  for (int nf = 0; nf < 4; ++nf) {
    float s = 0.f;
#pragma unroll
    for (int mt = 0; mt < 5; ++mt)
#pragma unroll
      for (int r = 0; r < 4; ++r) {
        float z = accf[mt][nf][r] - c_r[mt][r];
        s = fmaf(z, z, s);
      }
    s += __shfl_xor(s, 16);
    s += __shfl_xor(s, 32);  // all 4 lane-groups combined: full maha for col lr
    float g = 0.f;
    int t = t0 + nf * 16 + lr;
    if (l < 16) g = gamma[((size_t)b * TTOT + t) * KK + k];
    v = fmaf(g, dconst + 0.5f * s, v);
  }
  v = wave_sum(v);

  __shared__ float red[4];
  if (l == 0) red[w] = v;
  __syncthreads();
  if (threadIdx.x == 0)
    part[(b * 4 + tt) * KK + k] = red[0] + red[1] + red[2] + red[3];
}

// ---- K3: L regularizer (masked subjects only); one partial per block ----
__global__ __launch_bounds__(256) void k3_lreg(const float* __restrict__ L_subj,
                                               const float* __restrict__ L_pop,
                                               const float* __restrict__ ws,
                                               float* __restrict__ part) {
  int p = blockIdx.y;
  int chunk = blockIdx.x;  // 25 chunks x 1024 float4 per subject
  int pidx = p * 25 + chunk;
  if (ws[WS_MASK + p] == 0.f) {
    if (threadIdx.x == 0) part[pidx] = 0.f;
    return;
  }
  const float4* a4 = reinterpret_cast<const float4*>(L_subj) + (size_t)p * (KK * DD * DD / 4);
  const float4* b4 = reinterpret_cast<const float4*>(L_pop);
  float s = 0.f;
#pragma unroll
  for (int q = 0; q < 4; ++q) {
    int o = chunk * 1024 + q * 256 + threadIdx.x;
    float4 a = a4[o], bb = b4[o];
    float d0 = a.x - bb.x, d1 = a.y - bb.y, d2 = a.z - bb.z, d3 = a.w - bb.w;
    s += d0 * d0 + d1 * d1 + d2 * d2 + d3 * d3;
  }
  s = wave_sum(s);
  __shared__ float red[4];
  if ((threadIdx.x & 63) == 0) red[threadIdx.x >> 6] = s;
  __syncthreads();
  if (threadIdx.x == 0) part[pidx] = red[0] + red[1] + red[2] + red[3];
}

// ---- K3b: mu regularizer; one partial per block ----
__global__ __launch_bounds__(64) void k3_mureg(const float* __restrict__ mu_subj,
                                               const float* __restrict__ mu_pop,
                                               const float* __restrict__ ws,
                                               float* __restrict__ part) {
  int p = blockIdx.x;
  if (ws[WS_MASK + p] == 0.f) {
    if (threadIdx.x == 0) part[p] = 0.f;
    return;
  }
  const float4* a4 = reinterpret_cast<const float4*>(mu_subj) + (size_t)p * (KK * DD / 4);
  const float4* b4 = reinterpret_cast<const float4*>(mu_pop);
  float s = 0.f;
#pragma unroll
  for (int q = 0; q < 5; ++q) {
    int o = q * 64 + threadIdx.x;
    float4 a = a4[o], bb = b4[o];
    float d0 = a.x - bb.x, d1 = a.y - bb.y, d2 = a.z - bb.z, d3 = a.w - bb.w;
    s += d0 * d0 + d1 * d1 + d2 * d2 + d3 * d3;
  }
  s = wave_sum(s);
  if (threadIdx.x == 0) part[p] = s;
}

// ---- K4: reduce all partials, combine ----
__global__ __launch_bounds__(256) void k4_final(const float* __restrict__ ws,
                                                float* __restrict__ out) {
  int tid = threadIdx.x;
  float scale = ws[WS_NUNIQ] / 64.0f;

  float a = 0.f;
  for (int i = tid; i < 2048; i += 256) a += ws[WS_PART2 + i];
  float lr = 0.f;
  for (int i = tid; i < 1600; i += 256) lr += ws[WS_PART3L + i];
  float mr = 0.f;
  if (tid < 64) mr = ws[WS_PART3M + tid];

  float v = a / 32768.0f + scale * 0.05f * (lr + mr);
  v = wave_sum(v);
  __shared__ float red[4];
  if ((tid & 63) == 0) red[tid >> 6] = v;
  __syncthreads();
  if (tid == 0) out[0] = red[0] + red[1] + red[2] + red[3];
}

extern "C" void kernel_launch(void* const* d_in, const int* in_sizes, int n_in,
                              void* d_out, int out_size, void* d_ws, size_t ws_size,
                              hipStream_t stream) {
  const float* x       = (const float*)d_in[0];
  const float* mu_pop  = (const float*)d_in[1];
  const float* L_pop   = (const float*)d_in[2];
  const float* mu_subj = (const float*)d_in[3];
  const float* L_subj  = (const float*)d_in[4];
  const float* gamma   = (const float*)d_in[5];
  const int*   sids    = (const int*)d_in[6];
  float* out = (float*)d_out;
  float* ws  = (float*)d_ws;

  hipLaunchKernelGGL(k0_mask, dim3(1), dim3(64), 0, stream, sids, ws);
  hipLaunchKernelGGL(kx_cast, dim3(BB * TTOT * DD / 4 / 256), dim3(256), 0, stream, x, ws);
  hipLaunchKernelGGL(k1_inv, dim3(KK, BB), dim3(128), 0, stream, L_subj, mu_subj, sids, ws);
  hipLaunchKernelGGL(k2_mfma, dim3(KK, TTOT / 256, BB), dim3(256), 0, stream,
                     gamma, ws, ws + WS_PART2);
  hipLaunchKernelGGL(k3_lreg, dim3(25, PP), dim3(256), 0, stream,
                     L_subj, L_pop, ws, ws + WS_PART3L);
  hipLaunchKernelGGL(k3_mureg, dim3(PP), dim3(64), 0, stream,
                     mu_subj, mu_pop, ws, ws + WS_PART3M);
  hipLaunchKernelGGL(k4_final, dim3(1), dim3(256), 0, stream, ws, out);
}

// Round 9
// 76.365 us; speedup vs baseline: 1.2046x; 1.2046x over previous
//
#include <hip/hip_runtime.h>
#include <hip/hip_bf16.h>
#include <math.h>

#define BB 32
#define TTOT 1024
#define KK 16
#define DD 80
#define PP 64

// workspace layout (float offsets)
#define WS_NUNIQ  0        // 1
#define WS_MASK   8        // 64
#define WS_DCONST 128      // 512 = B*K
#define WS_CVEC   1024     // 512*80 -> ends 41984
#define WS_PART2  41984    // 2048 (k2 per-block partials) -> 44032
#define WS_PART3L 44032    // 1600 (k3_lreg per-block partials) -> 45632
#define WS_PART3M 45632    // 64 (k3_mureg per-block partials) -> 45696
#define WS_XBF16  46080    // bf16[32*1024*80] = 1,310,720 floats -> ends 1,356,800
#define WS_MINVB  1356800  // bf16[512*80*80]  = 1,638,400 floats -> ends 2,995,200 (12.0 MB)

typedef short bf16x8 __attribute__((ext_vector_type(8)));
typedef float f32x4 __attribute__((ext_vector_type(4)));

__device__ __forceinline__ float wave_sum(float v) {
#pragma unroll
  for (int o = 32; o > 0; o >>= 1) v += __shfl_down(v, o);
  return v;
}

__device__ __forceinline__ unsigned short f2bf(float f) {
  __hip_bfloat16 h = __float2bfloat16(f);
  return *reinterpret_cast<unsigned short*>(&h);
}

// ---- K0: subject mask + n_unique ----
__global__ void k0_mask(const int* __restrict__ sids, float* __restrict__ ws) {
  int tid = threadIdx.x;  // 64 threads, one per subject slot
  int found = 0;
  for (int b = 0; b < BB; ++b) found |= (sids[b] == tid) ? 1 : 0;
  ws[WS_MASK + tid] = (float)found;
  unsigned long long bal = __ballot(found != 0);
  if (tid == 0) ws[WS_NUNIQ] = (float)__popcll(bal);
}

// ---- KX: x fp32 -> bf16 (same layout) ----
__global__ __launch_bounds__(256) void kx_cast(const float* __restrict__ x,
                                               float* __restrict__ ws) {
  size_t idx = (size_t)blockIdx.x * 256 + threadIdx.x;  // one per 4 floats
  float4 v = reinterpret_cast<const float4*>(x)[idx];
  uint2 o;
  o.x = ((unsigned)f2bf(v.y) << 16) | f2bf(v.x);
  o.y = ((unsigned)f2bf(v.w) << 16) | f2bf(v.z);
  reinterpret_cast<uint2*>((__hip_bfloat16*)(ws + WS_XBF16))[idx] = o;
}

// ---- K1: per (b,k) triangular inverse; emit Minv as bf16, c fp32, dconst ----
// R8 lesson: occupancy is structurally capped (~640 waves total), so global
// loads inside the solve chain are latency-exposed. Fix: stage L into LDS once
// (coalesced float4, pipelined), then solve against LDS: uniform L reads are
// broadcast float4 (pad 84 keeps alignment), per-thread ym reads are stride-1
// (2-way aliasing = free). Per-thread live arrays are 16 elements, static idx.
__global__ __launch_bounds__(128, 1) void k1_inv(const float* __restrict__ L_subj,
                                                 const float* __restrict__ mu_subj,
                                                 const int* __restrict__ sids,
                                                 float* __restrict__ ws) {
  int k = blockIdx.x, b = blockIdx.y;
  int p = sids[b];
  const float* Lg = L_subj + ((size_t)(p * KK + k)) * DD * DD;
  const float* mug = mu_subj + (size_t)(p * KK + k) * DD;
  int bk = b * KK + k;

  __shared__ float Ls[DD * 84];        // staged L, stride 84 (16B-aligned rows)
  __shared__ float ys[DD * 81 + 64];   // Minv (fp32), stride 81; +64 OOB pad
  __shared__ float rdiag[DD];
  __shared__ float lgd[DD];

  int tid = threadIdx.x;

  // stage L: 1600 float4 coalesced reads, aligned float4 LDS writes
  {
    const float4* Lg4 = reinterpret_cast<const float4*>(Lg);
    for (int idx = tid; idx < DD * DD / 4; idx += 128) {
      float4 v = Lg4[idx];
      int r = idx / (DD / 4), c0 = (idx % (DD / 4)) * 4;
      *reinterpret_cast<float4*>(&Ls[r * 84 + c0]) = v;
    }
  }
  __syncthreads();

  if (tid < DD) {
    float dv = Ls[tid * 84 + tid];
    rdiag[tid] = 1.0f / dv;
    lgd[tid] = logf(dv);
  }
  __syncthreads();

  const int j = tid;  // column of Minv this thread solves: L y = e_j
  const bool act = j < DD;
  for (int ci = 0; ci < 5; ++ci) {
    const int r0 = ci * 16;
    float s[16];
#pragma unroll
    for (int ii = 0; ii < 16; ++ii) s[ii] = (r0 + ii == j) ? 1.0f : 0.0f;
    // cross-chunk contributions: L via uniform float4 broadcast, ym stride-1
    for (int cp = 0; cp < ci; ++cp) {
      float ym[16];
#pragma unroll
      for (int m = 0; m < 16; ++m) ym[m] = ys[(cp * 16 + m) * 81 + j];
#pragma unroll
      for (int ii = 0; ii < 16; ++ii) {
        const float4* Lr = reinterpret_cast<const float4*>(&Ls[(r0 + ii) * 84 + cp * 16]);
        float4 a0 = Lr[0], a1 = Lr[1], a2 = Lr[2], a3 = Lr[3];
        float t = s[ii];
        t = fmaf(-a0.x, ym[0], t);  t = fmaf(-a0.y, ym[1], t);
        t = fmaf(-a0.z, ym[2], t);  t = fmaf(-a0.w, ym[3], t);
        t = fmaf(-a1.x, ym[4], t);  t = fmaf(-a1.y, ym[5], t);
        t = fmaf(-a1.z, ym[6], t);  t = fmaf(-a1.w, ym[7], t);
        t = fmaf(-a2.x, ym[8], t);  t = fmaf(-a2.y, ym[9], t);
        t = fmaf(-a2.z, ym[10], t); t = fmaf(-a2.w, ym[11], t);
        t = fmaf(-a3.x, ym[12], t); t = fmaf(-a3.y, ym[13], t);
        t = fmaf(-a3.z, ym[14], t); t = fmaf(-a3.w, ym[15], t);
        s[ii] = t;
      }
    }
    // in-chunk 16x16 triangular solve; L reads are uniform LDS broadcast
    float yc[16];
#pragma unroll
    for (int ii = 0; ii < 16; ++ii) {
      float v = s[ii];
#pragma unroll
      for (int mm = 0; mm < 16; ++mm)
        if (mm < ii) v = fmaf(-Ls[(r0 + ii) * 84 + r0 + mm], yc[mm], v);
      yc[ii] = v * rdiag[r0 + ii];
    }
    if (act) {
#pragma unroll
      for (int ii = 0; ii < 16; ++ii) ys[(r0 + ii) * 81 + j] = yc[ii];
    }
  }
  __syncthreads();

  // coalesced bf16 write of Minv rows (2 bf16 per uint)
  unsigned* Mg = reinterpret_cast<unsigned*>(
      (__hip_bfloat16*)(ws + WS_MINVB) + (size_t)bk * DD * DD);
  for (int idx = tid; idx < DD * (DD / 2); idx += 128) {
    int i = idx / (DD / 2), jp = idx % (DD / 2);
    unsigned u = ((unsigned)f2bf(ys[i * 81 + 2 * jp + 1]) << 16) | f2bf(ys[i * 81 + 2 * jp]);
    Mg[idx] = u;
  }

  if (tid < DD) {
    int i = tid;
    float ci = 0.f;
#pragma unroll 8
    for (int jj = 0; jj < DD; ++jj) ci = fmaf(ys[i * 81 + jj], mug[jj], ci);
    ws[WS_CVEC + bk * DD + i] = ci;
  }
  if (tid == 0) {
    float s = 0.f;
    for (int i = 0; i < DD; ++i) s += lgd[i];
    ws[WS_DCONST + bk] = (float)(0.5 * 80.0 * 1.8378770664093453) + s;  // 0.5*D*ln(2pi)+logdet
  }
}

// ---- K2: MFMA main loss. Block = (k, ttile of 256, b); 4 waves x 64 t. ----
// Writes ONE partial per block (no global atomics).
__global__ __launch_bounds__(256) void k2_mfma(const float* __restrict__ gamma,
                                               const float* __restrict__ ws,
                                               float* __restrict__ part) {
  const int k = blockIdx.x, tt = blockIdx.y, b = blockIdx.z;
  const int w = threadIdx.x >> 6, l = threadIdx.x & 63;
  const int lg = l >> 4, lr = l & 15;
  const int bk = b * KK + k;

  const __hip_bfloat16* Xb = (const __hip_bfloat16*)(ws + WS_XBF16) + (size_t)b * TTOT * DD;
  const __hip_bfloat16* Mb = (const __hip_bfloat16*)(ws + WS_MINVB) + (size_t)bk * DD * DD;
  const float* cc = ws + WS_CVEC + bk * DD;
  const float dconst = ws[WS_DCONST + bk];

  const int t0 = tt * 256 + w * 64;  // wave's t base

  f32x4 accf[5][4] = {};  // [m-tile][n-frag]
#pragma unroll
  for (int c = 0; c < 3; ++c) {
    const int j = c * 32 + lg * 8;
    const bool dead = (c == 2) && (lg >= 2);  // j >= 80: zero-pad K to 96
    bf16x8 af[5], bf[4];
#pragma unroll
    for (int mt = 0; mt < 5; ++mt)
      af[mt] = dead ? (bf16x8){} : *(const bf16x8*)(Mb + (mt * 16 + lr) * DD + j);
#pragma unroll
    for (int nf = 0; nf < 4; ++nf)
      bf[nf] = dead ? (bf16x8){} : *(const bf16x8*)(Xb + (size_t)(t0 + nf * 16 + lr) * DD + j);
#pragma unroll
    for (int mt = 0; mt < 5; ++mt)
#pragma unroll
      for (int nf = 0; nf < 4; ++nf)
        accf[mt][nf] = __builtin_amdgcn_mfma_f32_16x16x32_bf16(af[mt], bf[nf], accf[mt][nf], 0, 0, 0);
  }

  // epilogue: maha per t, gamma-weighted accumulate
  float c_r[5][4];
#pragma unroll
  for (int mt = 0; mt < 5; ++mt)
#pragma unroll
    for (int r = 0; r < 4; ++r)
      c_r[mt][r] = cc[mt * 16 + lg * 4 + r];  // row i = mt*16 + lg*4 + r

  float v = 0.f;
#pragma unroll
  for (int nf = 0; nf < 4; ++nf) {
    float s = 0.f;
#pragma unroll
    for (int mt = 0; mt < 5; ++mt)
#pragma unroll
      for (int r = 0; r < 4; ++r) {
        float z = accf[mt][nf][r] - c_r[mt][r];
        s = fmaf(z, z, s);
      }
    s += __shfl_xor(s, 16);
    s += __shfl_xor(s, 32);  // all 4 lane-groups combined: full maha for col lr
    float g = 0.f;
    int t = t0 + nf * 16 + lr;
    if (l < 16) g = gamma[((size_t)b * TTOT + t) * KK + k];
    v = fmaf(g, dconst + 0.5f * s, v);
  }
  v = wave_sum(v);

  __shared__ float red[4];
  if (l == 0) red[w] = v;
  __syncthreads();
  if (threadIdx.x == 0)
    part[(b * 4 + tt) * KK + k] = red[0] + red[1] + red[2] + red[3];
}

// ---- K3: L regularizer (masked subjects only); one partial per block ----
__global__ __launch_bounds__(256) void k3_lreg(const float* __restrict__ L_subj,
                                               const float* __restrict__ L_pop,
                                               const float* __restrict__ ws,
                                               float* __restrict__ part) {
  int p = blockIdx.y;
  int chunk = blockIdx.x;  // 25 chunks x 1024 float4 per subject
  int pidx = p * 25 + chunk;
  if (ws[WS_MASK + p] == 0.f) {
    if (threadIdx.x == 0) part[pidx] = 0.f;
    return;
  }
  const float4* a4 = reinterpret_cast<const float4*>(L_subj) + (size_t)p * (KK * DD * DD / 4);
  const float4* b4 = reinterpret_cast<const float4*>(L_pop);
  float s = 0.f;
#pragma unroll
  for (int q = 0; q < 4; ++q) {
    int o = chunk * 1024 + q * 256 + threadIdx.x;
    float4 a = a4[o], bb = b4[o];
    float d0 = a.x - bb.x, d1 = a.y - bb.y, d2 = a.z - bb.z, d3 = a.w - bb.w;
    s += d0 * d0 + d1 * d1 + d2 * d2 + d3 * d3;
  }
  s = wave_sum(s);
  __shared__ float red[4];
  if ((threadIdx.x & 63) == 0) red[threadIdx.x >> 6] = s;
  __syncthreads();
  if (threadIdx.x == 0) part[pidx] = red[0] + red[1] + red[2] + red[3];
}

// ---- K3b: mu regularizer; one partial per block ----
__global__ __launch_bounds__(64) void k3_mureg(const float* __restrict__ mu_subj,
                                               const float* __restrict__ mu_pop,
                                               const float* __restrict__ ws,
                                               float* __restrict__ part) {
  int p = blockIdx.x;
  if (ws[WS_MASK + p] == 0.f) {
    if (threadIdx.x == 0) part[p] = 0.f;
    return;
  }
  const float4* a4 = reinterpret_cast<const float4*>(mu_subj) + (size_t)p * (KK * DD / 4);
  const float4* b4 = reinterpret_cast<const float4*>(mu_pop);
  float s = 0.f;
#pragma unroll
  for (int q = 0; q < 5; ++q) {
    int o = q * 64 + threadIdx.x;
    float4 a = a4[o], bb = b4[o];
    float d0 = a.x - bb.x, d1 = a.y - bb.y, d2 = a.z - bb.z, d3 = a.w - bb.w;
    s += d0 * d0 + d1 * d1 + d2 * d2 + d3 * d3;
  }
  s = wave_sum(s);
  if (threadIdx.x == 0) part[p] = s;
}

// ---- K4: reduce all partials, combine ----
__global__ __launch_bounds__(256) void k4_final(const float* __restrict__ ws,
                                                float* __restrict__ out) {
  int tid = threadIdx.x;
  float scale = ws[WS_NUNIQ] / 64.0f;

  float a = 0.f;
  for (int i = tid; i < 2048; i += 256) a += ws[WS_PART2 + i];
  float lr = 0.f;
  for (int i = tid; i < 1600; i += 256) lr += ws[WS_PART3L + i];
  float mr = 0.f;
  if (tid < 64) mr = ws[WS_PART3M + tid];

  float v = a / 32768.0f + scale * 0.05f * (lr + mr);
  v = wave_sum(v);
  __shared__ float red[4];
  if ((tid & 63) == 0) red[tid >> 6] = v;
  __syncthreads();
  if (tid == 0) out[0] = red[0] + red[1] + red[2] + red[3];
}

extern "C" void kernel_launch(void* const* d_in, const int* in_sizes, int n_in,
                              void* d_out, int out_size, void* d_ws, size_t ws_size,
                              hipStream_t stream) {
  const float* x       = (const float*)d_in[0];
  const float* mu_pop  = (const float*)d_in[1];
  const float* L_pop   = (const float*)d_in[2];
  const float* mu_subj = (const float*)d_in[3];
  const float* L_subj  = (const float*)d_in[4];
  const float* gamma   = (const float*)d_in[5];
  const int*   sids    = (const int*)d_in[6];
  float* out = (float*)d_out;
  float* ws  = (float*)d_ws;

  hipLaunchKernelGGL(k0_mask, dim3(1), dim3(64), 0, stream, sids, ws);
  hipLaunchKernelGGL(kx_cast, dim3(BB * TTOT * DD / 4 / 256), dim3(256), 0, stream, x, ws);
  hipLaunchKernelGGL(k1_inv, dim3(KK, BB), dim3(128), 0, stream, L_subj, mu_subj, sids, ws);
  hipLaunchKernelGGL(k2_mfma, dim3(KK, TTOT / 256, BB), dim3(256), 0, stream,
                     gamma, ws, ws + WS_PART2);
  hipLaunchKernelGGL(k3_lreg, dim3(25, PP), dim3(256), 0, stream,
                     L_subj, L_pop, ws, ws + WS_PART3L);
  hipLaunchKernelGGL(k3_mureg, dim3(PP), dim3(64), 0, stream,
                     mu_subj, mu_pop, ws, ws + WS_PART3M);
  hipLaunchKernelGGL(k4_final, dim3(1), dim3(256), 0, stream, ws, out);
}